// Round 2
// baseline (1007.679 us; speedup 1.0000x reference)
//
#include <hip/hip_runtime.h>
#include <hip/hip_bf16.h>
#include <stdint.h>

#define T_TOK 2048
#define HDIM  2048
#define IDIM  1024
#define NEXP  16
#define SCALING 2.5f

typedef __attribute__((ext_vector_type(8))) short bf16x8;
typedef __attribute__((ext_vector_type(4))) float f32x4;

static __device__ __forceinline__ unsigned short f2bf(float f) {
    uint32_t u = __float_as_uint(f);
    u += 0x7FFF + ((u >> 16) & 1);
    return (unsigned short)(u >> 16);
}

#define GLD_LDS16(g, l) \
    __builtin_amdgcn_global_load_lds((const __attribute__((address_space(1))) uint32_t*)(g), \
                                     (__attribute__((address_space(3))) uint32_t*)(l), 16, 0, 0)

// ---------------- fp32 -> bf16 convert of hidden_states ----------------
__global__ __launch_bounds__(256) void cvt_k(const float* __restrict__ x,
                                             unsigned short* __restrict__ o) {
    int i = (blockIdx.x * 256 + threadIdx.x) * 8;
    float4 f0 = *(const float4*)(x + i);
    float4 f1 = *(const float4*)(x + i + 4);
    union { unsigned short h[8]; uint4 v; } u;
    u.h[0] = f2bf(f0.x); u.h[1] = f2bf(f0.y); u.h[2] = f2bf(f0.z); u.h[3] = f2bf(f0.w);
    u.h[4] = f2bf(f1.x); u.h[5] = f2bf(f1.y); u.h[6] = f2bf(f1.z); u.h[7] = f2bf(f1.w);
    *(uint4*)(o + i) = u.v;
}

// ---------------- routing (fp32 exact) ----------------
__global__ __launch_bounds__(256) void route_k(const float* __restrict__ x,
                                               const float* __restrict__ gw,
                                               const float* __restrict__ bias,
                                               int* __restrict__ tokl,
                                               float* __restrict__ twl,
                                               int* __restrict__ cnt) {
    __shared__ float slog[NEXP];
    int t = blockIdx.x;
    int tid = threadIdx.x;
    int e = tid >> 4, r = tid & 15;
    const float* xp = x + (size_t)t * HDIM;
    const float* wp = gw + (size_t)e * HDIM;
    float p = 0.f;
    for (int j = r; j < HDIM; j += 16) p += xp[j] * wp[j];
    for (int off = 8; off; off >>= 1) p += __shfl_down(p, off, 16);
    if (r == 0) slog[e] = p;
    __syncthreads();
    if (tid == 0) {
        float sc[NEXP], bi[NEXP];
        for (int i = 0; i < NEXP; i++) {
            sc[i] = 1.f / (1.f + expf(-slog[i]));
            bi[i] = sc[i] + bias[i];
        }
        // group scores = sum of top-2 within each group of 4
        float gsc[4];
        for (int g = 0; g < 4; g++) {
            float v0 = bi[g*4+0], v1 = bi[g*4+1], v2 = bi[g*4+2], v3 = bi[g*4+3];
            float hi01 = fmaxf(v0, v1), lo01 = fminf(v0, v1);
            float hi23 = fmaxf(v2, v3), lo23 = fminf(v2, v3);
            float top1 = fmaxf(hi01, hi23);
            float sec  = fmaxf(fminf(hi01, hi23), (hi01 >= hi23) ? lo01 : lo23);
            gsc[g] = top1 + sec;
        }
        // top-2 groups (stable: strict > keeps lower index on tie)
        int g0 = 0; for (int g = 1; g < 4; g++) if (gsc[g] > gsc[g0]) g0 = g;
        int g1 = (g0 == 0) ? 1 : 0;
        for (int g = 0; g < 4; g++) if (g != g0 && gsc[g] > gsc[g1]) g1 = g;
        float mk[NEXP];
        for (int i = 0; i < NEXP; i++) {
            int gg = i >> 2;
            mk[i] = (gg == g0 || gg == g1) ? bi[i] : -INFINITY;
        }
        int sel[4]; float wv[4]; float wsum = 0.f;
        for (int k = 0; k < 4; k++) {
            int bmax = 0; float bv = -INFINITY;
            for (int i = 0; i < NEXP; i++) if (mk[i] > bv) { bv = mk[i]; bmax = i; }
            sel[k] = bmax; mk[bmax] = -INFINITY;
            wv[k] = sc[bmax]; wsum += sc[bmax];
        }
        float scale = SCALING / (wsum + 1e-20f);
        for (int k = 0; k < 4; k++) {
            int ee = sel[k];
            int slot = atomicAdd(&cnt[ee], 1);
            tokl[ee * T_TOK + slot] = t;
            twl[ee * T_TOK + slot] = wv[k] * scale;
        }
    }
}

// ---------------- GEMM1: act = silu(Xe @ G^T) * (Xe @ U^T) ----------------
// grid: 17 * 16(mt) * 16(nt) = 4352 blocks; B rows interleaved gate/up.
__global__ __launch_bounds__(256) void gemm1_k(const unsigned short* __restrict__ Xbf,
                                               const float* __restrict__ gate_w,
                                               const float* __restrict__ up_w,
                                               const float* __restrict__ sh_gate,
                                               const float* __restrict__ sh_up,
                                               const int* __restrict__ tokl,
                                               const int* __restrict__ cnt,
                                               unsigned short* __restrict__ act) {
    __shared__ unsigned short lsA[2][128 * 64];
    __shared__ unsigned short lsB[2][128 * 64];
    int b = blockIdx.x;
    int swz = (b & 7) * 544 + (b >> 3);       // 4352/8 = 544, bijective XCD swizzle
    int mt = swz & 15, nt = (swz >> 4) & 15, e = swz >> 8;
    int C = (e == NEXP) ? T_TOK : cnt[e];
    int m0 = mt * 128;
    if (m0 >= C) return;
    int tid = threadIdx.x;

    // A staging (bf16, gathered rows, global_load_lds with pre-swizzled source)
    int c8 = tid & 7, rr = tid >> 3;          // chunk-in-row, row-in-32
    int swzc = c8 ^ (rr & 7);
    const char* aA[4];
    for (int i = 0; i < 4; i++) {
        int slot = m0 + i * 32 + rr;
        int sl = (slot < C) ? slot : (C - 1);
        int tk = (e == NEXP) ? sl : tokl[e * T_TOK + sl];
        aA[i] = (const char*)Xbf + ((size_t)tk * HDIM + (size_t)swzc * 8) * 2;
    }
    // B staging (fp32 -> bf16, 8 rows/thread-pass)
    int bg = tid & 15, br0 = tid >> 4;
    const float* pB[8];
    int wOffB[8];
    for (int p = 0; p < 8; p++) {
        int row = p * 16 + br0;
        int f = nt * 64 + (row >> 1);
        const float* base;
        if (e == NEXP) base = (row & 1) ? sh_up : sh_gate;
        else base = ((row & 1) ? up_w : gate_w) + (size_t)e * IDIM * HDIM;
        pB[p] = base + (size_t)f * HDIM + bg * 4;
        wOffB[p] = row * 128 + (((bg >> 1) ^ (row & 7)) << 4) + ((bg & 1) << 3);
    }

    int lane = tid & 63, wid = tid >> 6;
    int wrow = (wid >> 1) << 6, wcol = (wid & 1) << 6;
    int fr = lane & 15, kg = lane >> 4;

    f32x4 acc[4][4];
#pragma unroll
    for (int m = 0; m < 4; m++)
#pragma unroll
        for (int n = 0; n < 4; n++) acc[m][n] = (f32x4){0.f, 0.f, 0.f, 0.f};

    auto stage = [&](int kt, int bf) {
        size_t kb = (size_t)kt * 128;
#pragma unroll
        for (int i = 0; i < 4; i++)
            GLD_LDS16(aA[i] + kb, (char*)&lsA[bf][0] + i * 4096 + tid * 16);
        size_t kf = (size_t)kt * 64;
        char* lB = (char*)&lsB[bf][0];
#pragma unroll
        for (int p = 0; p < 8; p++) {
            float4 f = *(const float4*)(pB[p] + kf);
            uint64_t v = (uint64_t)f2bf(f.x) | ((uint64_t)f2bf(f.y) << 16)
                       | ((uint64_t)f2bf(f.z) << 32) | ((uint64_t)f2bf(f.w) << 48);
            *(uint64_t*)(lB + wOffB[p]) = v;
        }
    };
    auto compute = [&](int bf) {
        const char* lA = (const char*)&lsA[bf][0];
        const char* lB = (const char*)&lsB[bf][0];
#pragma unroll
        for (int h = 0; h < 2; h++) {
            bf16x8 av[4], bv[4];
#pragma unroll
            for (int m = 0; m < 4; m++)
                av[m] = *(const bf16x8*)(lA + (wrow + m * 16 + fr) * 128 + (((h * 4 + kg) ^ (fr & 7)) << 4));
#pragma unroll
            for (int n = 0; n < 4; n++)
                bv[n] = *(const bf16x8*)(lB + (wcol + n * 16 + fr) * 128 + (((h * 4 + kg) ^ (fr & 7)) << 4));
#pragma unroll
            for (int m = 0; m < 4; m++)
#pragma unroll
                for (int n = 0; n < 4; n++)
                    acc[m][n] = __builtin_amdgcn_mfma_f32_16x16x32_bf16(av[m], bv[n], acc[m][n], 0, 0, 0);
        }
    };

    stage(0, 0);
    __syncthreads();
    int cur = 0;
    for (int kt = 0; kt < 32; ++kt) {
        if (kt + 1 < 32) stage(kt + 1, cur ^ 1);
        compute(cur);
        __syncthreads();
        cur ^= 1;
    }

    unsigned short* actE = act + (size_t)e * T_TOK * IDIM;
#pragma unroll
    for (int m = 0; m < 4; m++)
#pragma unroll
        for (int n = 0; n < 4; n++)
#pragma unroll
            for (int q = 0; q < 4; q++) {
                float v = acc[m][n][q];
                float pu = __shfl_xor(v, 1, 64);
                int row = wrow + m * 16 + kg * 4 + q;
                int slot = m0 + row;
                int col = wcol + n * 16 + fr;
                if (!(lane & 1) && slot < C) {
                    float g = v, u = pu;
                    float a = g / (1.f + __expf(-g)) * u;
                    int j = nt * 64 + (col >> 1);
                    actE[(size_t)slot * IDIM + j] = f2bf(a);
                }
            }
}

// ---------------- GEMM2: out[tok] += w * (act_e @ D^T) ----------------
__global__ __launch_bounds__(256) void gemm2_k(const unsigned short* __restrict__ act,
                                               const float* __restrict__ down_w,
                                               const float* __restrict__ sh_down,
                                               const int* __restrict__ tokl,
                                               const float* __restrict__ twl,
                                               const int* __restrict__ cnt,
                                               float* __restrict__ out) {
    __shared__ unsigned short lsA[2][128 * 64];
    __shared__ unsigned short lsB[2][128 * 64];
    int b = blockIdx.x;
    int swz = (b & 7) * 544 + (b >> 3);
    int mt = swz & 15, nt = (swz >> 4) & 15, e = swz >> 8;
    int C = (e == NEXP) ? T_TOK : cnt[e];
    int m0 = mt * 128;
    if (m0 >= C) return;
    int nb = nt * 128;
    int tid = threadIdx.x;

    const unsigned short* actE = act + (size_t)e * T_TOK * IDIM;
    int c8 = tid & 7, rr = tid >> 3;
    int swzc = c8 ^ (rr & 7);
    const char* aA[4];
    for (int i = 0; i < 4; i++) {
        int slot = m0 + i * 32 + rr;             // always < 2048, poison rows masked later
        aA[i] = (const char*)actE + ((size_t)slot * IDIM + (size_t)swzc * 8) * 2;
    }
    int bg = tid & 15, br0 = tid >> 4;
    const float* pB[8];
    int wOffB[8];
    const float* dbase = (e == NEXP) ? sh_down : (down_w + (size_t)e * HDIM * IDIM);
    for (int p = 0; p < 8; p++) {
        int row = p * 16 + br0;
        pB[p] = dbase + (size_t)(nb + row) * IDIM + bg * 4;
        wOffB[p] = row * 128 + (((bg >> 1) ^ (row & 7)) << 4) + ((bg & 1) << 3);
    }

    int lane = tid & 63, wid = tid >> 6;
    int wrow = (wid >> 1) << 6, wcol = (wid & 1) << 6;
    int fr = lane & 15, kg = lane >> 4;

    f32x4 acc[4][4];
#pragma unroll
    for (int m = 0; m < 4; m++)
#pragma unroll
        for (int n = 0; n < 4; n++) acc[m][n] = (f32x4){0.f, 0.f, 0.f, 0.f};

    auto stage = [&](int kt, int bf) {
        size_t kb = (size_t)kt * 128;
#pragma unroll
        for (int i = 0; i < 4; i++)
            GLD_LDS16(aA[i] + kb, (char*)&lsA[bf][0] + i * 4096 + tid * 16);
        size_t kf = (size_t)kt * 64;
        char* lB = (char*)&lsB[bf][0];
#pragma unroll
        for (int p = 0; p < 8; p++) {
            float4 f = *(const float4*)(pB[p] + kf);
            uint64_t v = (uint64_t)f2bf(f.x) | ((uint64_t)f2bf(f.y) << 16)
                       | ((uint64_t)f2bf(f.z) << 32) | ((uint64_t)f2bf(f.w) << 48);
            *(uint64_t*)(lB + wOffB[p]) = v;
        }
    };
    auto compute = [&](int bf) {
        const char* lA = (const char*)&lsA[bf][0];
        const char* lB = (const char*)&lsB[bf][0];
#pragma unroll
        for (int h = 0; h < 2; h++) {
            bf16x8 av[4], bv[4];
#pragma unroll
            for (int m = 0; m < 4; m++)
                av[m] = *(const bf16x8*)(lA + (wrow + m * 16 + fr) * 128 + (((h * 4 + kg) ^ (fr & 7)) << 4));
#pragma unroll
            for (int n = 0; n < 4; n++)
                bv[n] = *(const bf16x8*)(lB + (wcol + n * 16 + fr) * 128 + (((h * 4 + kg) ^ (fr & 7)) << 4));
#pragma unroll
            for (int m = 0; m < 4; m++)
#pragma unroll
                for (int n = 0; n < 4; n++)
                    acc[m][n] = __builtin_amdgcn_mfma_f32_16x16x32_bf16(av[m], bv[n], acc[m][n], 0, 0, 0);
        }
    };

    stage(0, 0);
    __syncthreads();
    int cur = 0;
    for (int kt = 0; kt < 16; ++kt) {
        if (kt + 1 < 16) stage(kt + 1, cur ^ 1);
        compute(cur);
        __syncthreads();
        cur ^= 1;
    }

#pragma unroll
    for (int m = 0; m < 4; m++)
#pragma unroll
        for (int q = 0; q < 4; q++) {
            int row = wrow + m * 16 + kg * 4 + q;
            int slot = m0 + row;
            if (slot >= C) continue;
            int tk; float wg;
            if (e == NEXP) { tk = slot; wg = 1.f; }
            else { tk = tokl[e * T_TOK + slot]; wg = twl[e * T_TOK + slot]; }
            float* o = out + (size_t)tk * HDIM + nb + wcol + fr;
#pragma unroll
            for (int n = 0; n < 4; n++)
                atomicAdd(o + n * 16, wg * acc[m][n][q]);
        }
}

extern "C" void kernel_launch(void* const* d_in, const int* in_sizes, int n_in,
                              void* d_out, int out_size, void* d_ws, size_t ws_size,
                              hipStream_t stream) {
    const float* x      = (const float*)d_in[0];
    const float* gw     = (const float*)d_in[1];
    const float* bias   = (const float*)d_in[2];
    const float* gate_w = (const float*)d_in[3];
    const float* up_w   = (const float*)d_in[4];
    const float* down_w = (const float*)d_in[5];
    const float* shg    = (const float*)d_in[6];
    const float* shu    = (const float*)d_in[7];
    const float* shd    = (const float*)d_in[8];
    float* out = (float*)d_out;
    char* ws = (char*)d_ws;

    unsigned short* Xbf  = (unsigned short*)ws;                         // 8 MB
    unsigned short* act  = (unsigned short*)(ws + 8388608);             // 68 MB (17 experts)
    int*            tokl = (int*)(ws + 8388608 + 71303168);             // 128 KB
    float*          twl  = (float*)(ws + 8388608 + 71303168 + 131072);  // 128 KB
    int*            cnt  = (int*)(ws + 8388608 + 71303168 + 262144);    // 64 B

    hipMemsetAsync(out, 0, (size_t)out_size * 4, stream);
    hipMemsetAsync(cnt, 0, 64, stream);
    cvt_k<<<2048, 256, 0, stream>>>(x, Xbf);
    route_k<<<2048, 256, 0, stream>>>(x, gw, bias, tokl, twl, cnt);
    gemm1_k<<<4352, 256, 0, stream>>>(Xbf, gate_w, up_w, shg, shu, tokl, cnt, act);
    gemm2_k<<<4352, 256, 0, stream>>>(act, down_w, shd, tokl, twl, cnt, out);
}